// Round 12
// baseline (89.707 us; speedup 1.0000x reference)
//
#include <hip/hip_runtime.h>

// ConvCapsLayer: A=32,B=32,K=3,P=4,STRIDE=2,ITERS=3 — fp32 in/out
// x: (2,32,32,512) f32   weights: (288,32,16) f32   out: (450,512) f32
//
// R12 = R11 + LDS-staged x. Block = 256 thr = 4 waves = 4 j's sharing one
// patch n. The block stages the patch's 9 pixel rows (9 KB bf16) into LDS
// once (1 barrier), transform reads x from LDS (ds_read_b128, no L2
// round-trips; 4x less global x traffic). w reads stay lane-contiguous bf16
// global. Wave owns (n,j); lane owns i = lane+64k, k=0..4 (k=4 only
// lane<32); v[5][8] packed v2f in registers. Unnormalized softmax (SE rides
// the butterfly), split-first butterfly. it=0 c2 folded into transform.
//   xt_bf[pixel][a][16]  (4 MB, cast)     wt_bf[j][k][lane][16] (320 KB)
// LESSON (R4, R10): live set ~84-100 VGPR. Never bound/structure below it —
// 64-VGPR cap or recompute-v both produced 76-170 MB scratch spill traffic.

#define OH 15
#define OW 15
#define EPS_ 1e-8f

#define XT_ELEMS (2 * 32 * 32 * 512)        // 2,097,152 bf16 (4 MB)
#define WT_ELEMS (32 * 5 * 64 * 16)         // 163,840 bf16 (320 KB)

typedef float v2f __attribute__((ext_vector_type(2)));

__device__ __forceinline__ v2f pfma(float a, v2f b, v2f c) {
    return __builtin_elementwise_fma((v2f){a, a}, b, c);
}
__device__ __forceinline__ float b_lo(unsigned int u) {
    union { unsigned int i; float f; } c; c.i = u << 16; return c.f;
}
__device__ __forceinline__ float b_hi(unsigned int u) {
    union { unsigned int i; float f; } c; c.i = u & 0xFFFF0000u; return c.f;
}
__device__ __forceinline__ unsigned short f2bf(float f) {
    union { float f; unsigned int i; } c; c.f = f;
    return (unsigned short)((c.i + 0x7FFFu + ((c.i >> 16) & 1u)) >> 16); // RNE
}

// merged staging: [0, XT_ELEMS) casts x; [XT_ELEMS, +WT_ELEMS) permutes w
__global__ __launch_bounds__(256) void stage_kernel(
    const float* __restrict__ x, const float* __restrict__ w,
    unsigned short* __restrict__ xt, unsigned short* __restrict__ wt)
{
    const int tid = blockIdx.x * 256 + threadIdx.x;
    if (tid < XT_ELEMS) {
        xt[tid] = f2bf(x[tid]);
    } else {
        const int t2 = tid - XT_ELEMS;      // over WT_ELEMS
        const int j  = t2 / 5120;
        const int r  = t2 - j * 5120;
        const int k  = r >> 10;
        const int L  = (r >> 4) & 63;
        const int e  = r & 15;
        const int i  = L + 64 * k;
        wt[t2] = (i < 288) ? f2bf(w[(size_t)i * 512 + j * 16 + e])
                           : (unsigned short)0;
    }
}

template <bool PERM>
__global__ __launch_bounds__(256, 3) void convcaps_kernel(
    const void* __restrict__ xp,   // PERM ? bf16 xt : f32 x
    const void* __restrict__ wp_,  // PERM ? bf16 wt : f32 w
    float* __restrict__ out)       // (450,512)
{
    const int blk  = blockIdx.x;      // 0..3599
    const int n    = blk >> 3;        // patch 0..449
    const int jg   = blk & 7;
    const int t    = threadIdx.x;
    const int wv   = t >> 6;          // 0..3
    const int lane = t & 63;
    const int j    = jg * 4 + wv;     // out capsule 0..31

    const int batch = n / (OH * OW);
    const int rem   = n - batch * OH * OW;
    const int oy    = rem / OW;
    const int ox    = rem - oy * OW;

    const bool has5 = (lane < 32);

    __shared__ unsigned short xlds[9 * 512];   // 9 pixel rows, 9216 B

    if (PERM) {
        // cooperative stage: row p (1024 B) = 64 lanes x 16 B
        const unsigned short* xt = (const unsigned short*)xp;
        const int pixbase = (batch * 32 + oy * 2) * 32 + ox * 2;
        for (int p = wv; p < 9; p += 4) {
            const int kh = p / 3;
            const int kw = p - kh * 3;
            const unsigned short* src =
                xt + ((size_t)(pixbase + kh * 32 + kw)) * 512 + lane * 8;
            *(uint4*)&xlds[p * 512 + lane * 8] = *(const uint4*)src;
        }
        __syncthreads();
    }

    v2f v[5][8];                      // v[k][p*2+qq]
    v2f c2i[8];                       // it=0 weighted sum (uniform r)
#pragma unroll
    for (int m = 0; m < 8; ++m) c2i[m] = (v2f){0.f, 0.f};
    // inactive 5th slot: logit = -inf so exp -> 0 (drops has5 selects later)
    float logit[5] = {0.f, 0.f, 0.f, 0.f, has5 ? 0.f : -1e30f};

    // ---- v[k] = X_i(4x4) * W_ij(4x4), i = lane + 64k ----
#pragma unroll
    for (int k = 0; k < 5; ++k) {
        if (k == 4 && !has5) {
#pragma unroll
            for (int m = 0; m < 8; ++m) v[4][m] = (v2f){0.f, 0.f};
        } else {
            const int i  = lane + 64 * k;
            const int a  = i & 31;
            const int kw = (i >> 5) % 3;
            const int kh = i / 96;

            float xr[16];
            v2f wr2[4][2];
            if (PERM) {
                // x from LDS: xlds[(kh*3+kw)*512 + a*16 ..+15], 32B contiguous
                const uint4* xb = reinterpret_cast<const uint4*>(
                    xlds + (kh * 3 + kw) * 512 + a * 16);
                uint4 u0 = xb[0], u1 = xb[1];
                xr[0]=b_lo(u0.x); xr[1]=b_hi(u0.x); xr[2]=b_lo(u0.y); xr[3]=b_hi(u0.y);
                xr[4]=b_lo(u0.z); xr[5]=b_hi(u0.z); xr[6]=b_lo(u0.w); xr[7]=b_hi(u0.w);
                xr[8]=b_lo(u1.x); xr[9]=b_hi(u1.x); xr[10]=b_lo(u1.y); xr[11]=b_hi(u1.y);
                xr[12]=b_lo(u1.z); xr[13]=b_hi(u1.z); xr[14]=b_lo(u1.w); xr[15]=b_hi(u1.w);
                // wt[j][k][lane][16] bf16: 32B contiguous per lane
                const uint4* wb = reinterpret_cast<const uint4*>(
                    (const unsigned short*)wp_ + (((size_t)j * 5 + k) * 64 + lane) * 16);
                uint4 q0 = wb[0], q1 = wb[1];
                wr2[0][0] = (v2f){b_lo(q0.x), b_hi(q0.x)};
                wr2[0][1] = (v2f){b_lo(q0.y), b_hi(q0.y)};
                wr2[1][0] = (v2f){b_lo(q0.z), b_hi(q0.z)};
                wr2[1][1] = (v2f){b_lo(q0.w), b_hi(q0.w)};
                wr2[2][0] = (v2f){b_lo(q1.x), b_hi(q1.x)};
                wr2[2][1] = (v2f){b_lo(q1.y), b_hi(q1.y)};
                wr2[3][0] = (v2f){b_lo(q1.z), b_hi(q1.z)};
                wr2[3][1] = (v2f){b_lo(q1.w), b_hi(q1.w)};
            } else {
                const int h  = oy * 2 + kh;
                const int wc = ox * 2 + kw;
                const int pixel = (batch * 32 + h) * 32 + wc;
                const float4* xv = reinterpret_cast<const float4*>(
                    (const float*)xp + ((size_t)pixel * 512 + a * 16));
                float4 x0 = xv[0], x1 = xv[1], x2 = xv[2], x3 = xv[3];
                float t_[16] = { x0.x,x0.y,x0.z,x0.w, x1.x,x1.y,x1.z,x1.w,
                                 x2.x,x2.y,x2.z,x2.w, x3.x,x3.y,x3.z,x3.w };
#pragma unroll
                for (int e = 0; e < 16; ++e) xr[e] = t_[e];
                const float4* wq = reinterpret_cast<const float4*>(
                    (const float*)wp_ + ((size_t)i * 32 + j) * 16);
                float4 w0 = wq[0], w1 = wq[1], w2 = wq[2], w3 = wq[3];
                wr2[0][0]=(v2f){w0.x,w0.y}; wr2[0][1]=(v2f){w0.z,w0.w};
                wr2[1][0]=(v2f){w1.x,w1.y}; wr2[1][1]=(v2f){w1.z,w1.w};
                wr2[2][0]=(v2f){w2.x,w2.y}; wr2[2][1]=(v2f){w2.z,w2.w};
                wr2[3][0]=(v2f){w3.x,w3.y}; wr2[3][1]=(v2f){w3.z,w3.w};
            }

#pragma unroll
            for (int p = 0; p < 4; ++p) {
#pragma unroll
                for (int qq = 0; qq < 2; ++qq) {
                    v2f acc = (v2f){0.f, 0.f};
                    acc = pfma(xr[p*4+0], wr2[0][qq], acc);
                    acc = pfma(xr[p*4+1], wr2[1][qq], acc);
                    acc = pfma(xr[p*4+2], wr2[2][qq], acc);
                    acc = pfma(xr[p*4+3], wr2[3][qq], acc);
                    v[k][p*2+qq] = acc;
                }
            }
#pragma unroll
            for (int m = 0; m < 8; ++m) c2i[m] += v[k][m];  // it=0 sum
        }
    }

#pragma unroll
    for (int it = 0; it < 3; ++it) {
        v2f c2[8];
        float se_loc;
        if (it == 0) {
#pragma unroll
            for (int m = 0; m < 8; ++m) c2[m] = c2i[m];
            se_loc = 0.f;  // normalizer is 288 (softmax of zeros)
        } else {
            const float e0 = __expf(logit[0]), e1 = __expf(logit[1]);
            const float e2 = __expf(logit[2]), e3 = __expf(logit[3]);
            const float e4 = __expf(logit[4]);   // 0 for lanes >= 32
#pragma unroll
            for (int m = 0; m < 8; ++m)
                c2[m] = pfma(e0, v[0][m],
                        pfma(e1, v[1][m],
                        pfma(e2, v[2][m],
                        pfma(e3, v[3][m],
                        pfma(e4, v[4][m], (v2f){0.f, 0.f})))));
            se_loc = e0 + e1 + e2 + e3 + e4;
        }

        float c[16];
#pragma unroll
        for (int m = 0; m < 8; ++m) { c[2*m] = c2[m].x; c[2*m+1] = c2[m].y; }

        // ---- split-first butterfly: comp bit b -> lane bit b ----
        float seR = se_loc;
        float s8[8];
        {
            const bool b = lane & 1;
#pragma unroll
            for (int m = 0; m < 8; ++m) {
                float send = b ? c[2*m]   : c[2*m+1];
                float keep = b ? c[2*m+1] : c[2*m];
                s8[m] = keep + __shfl_xor(send, 1);
            }
            if (it > 0) seR += __shfl_xor(seR, 1);
        }
        float s4[4];
        {
            const bool b = (lane >> 1) & 1;
#pragma unroll
            for (int m = 0; m < 4; ++m) {
                float send = b ? s8[2*m]   : s8[2*m+1];
                float keep = b ? s8[2*m+1] : s8[2*m];
                s4[m] = keep + __shfl_xor(send, 2);
            }
            if (it > 0) seR += __shfl_xor(seR, 2);
        }
        float s2v[2];
        {
            const bool b = (lane >> 2) & 1;
#pragma unroll
            for (int m = 0; m < 2; ++m) {
                float send = b ? s4[2*m]   : s4[2*m+1];
                float keep = b ? s4[2*m+1] : s4[2*m];
                s2v[m] = keep + __shfl_xor(send, 4);
            }
            if (it > 0) seR += __shfl_xor(seR, 4);
        }
        float s1;
        {
            const bool b = (lane >> 3) & 1;
            float send = b ? s2v[0] : s2v[1];
            float keep = b ? s2v[1] : s2v[0];
            s1 = keep + __shfl_xor(send, 8);
            if (it > 0) seR += __shfl_xor(seR, 8);
        }
        s1 += __shfl_xor(s1, 16);  if (it > 0) seR += __shfl_xor(seR, 16);
        s1 += __shfl_xor(s1, 32);  if (it > 0) seR += __shfl_xor(seR, 32);
        // s1 = sum_i (e_i or 1) * v_i[comp], comp = lane&15 ; seR = SE

        const float s = (it == 0) ? s1 * (1.0f / 288.0f) : s1 / seR;

        // ---- squash ----
        float t2 = s * s;
        t2 += __shfl_xor(t2, 1);
        t2 += __shfl_xor(t2, 2);
        t2 += __shfl_xor(t2, 4);
        t2 += __shfl_xor(t2, 8);
        const float n2 = t2;
        const float scale = n2 / ((1.0f + n2) * sqrtf(n2 + EPS_));
        const float pval = s * scale;   // comp (lane&15) of p

        if (it < 2) {
            float p[16];
#pragma unroll
            for (int q = 0; q < 16; ++q) p[q] = __shfl(pval, q);
            v2f p2[8];
#pragma unroll
            for (int m = 0; m < 8; ++m) p2[m] = (v2f){p[2*m], p[2*m+1]};
#pragma unroll
            for (int k = 0; k < 5; ++k) {
                v2f acc = (v2f){0.f, 0.f};
#pragma unroll
                for (int m = 0; m < 8; ++m)
                    acc = __builtin_elementwise_fma(v[k][m], p2[m], acc);
                logit[k] += acc.x + acc.y;
            }
        } else {
            if (lane < 16)
                out[(size_t)n * 512 + j * 16 + lane] = pval;
        }
    }
}

extern "C" void kernel_launch(void* const* d_in, const int* in_sizes, int n_in,
                              void* d_out, int out_size, void* d_ws, size_t ws_size,
                              hipStream_t stream) {
    const float* x = (const float*)d_in[0];
    const float* w = (const float*)d_in[1];
    float* out = (float*)d_out;
    const int nblocks = 450 * 8;   // 4 waves/block (4 j's), one patch n/block

    const size_t need = (size_t)(XT_ELEMS + WT_ELEMS) * sizeof(unsigned short);
    if (d_ws != nullptr && ws_size >= need) {
        unsigned short* xt = (unsigned short*)d_ws;
        unsigned short* wt = xt + XT_ELEMS;
        stage_kernel<<<(XT_ELEMS + WT_ELEMS) / 256, 256, 0, stream>>>(x, w, xt, wt);
        convcaps_kernel<true><<<nblocks, 256, 0, stream>>>(xt, wt, out);
    } else {
        convcaps_kernel<false><<<nblocks, 256, 0, stream>>>(x, w, out);
    }
}

// Round 13
// 86.011 us; speedup vs baseline: 1.0430x; 1.0430x over previous
//
#include <hip/hip_runtime.h>

// ConvCapsLayer: A=32,B=32,K=3,P=4,STRIDE=2,ITERS=3 — fp32 in/out
// x: (2,32,32,512) f32   weights: (288,32,16) f32   out: (450,512) f32
//
// R13 = R11 verbatim (best measured: 86.3 µs). Structure: one WAVE per
// (n, j), 64-thr blocks; lane owns i = lane+64k, k=0..4 (k=4 only lane<32);
// v[5][8] packed v2f in registers; bf16-staged inputs (halves TA lines):
//   xt_bf[pixel][a][16]  (4 MB, cast)     wt_bf[j][k][lane][16] (320 KB)
// Unnormalized softmax (SE rides butterfly), split-first butterfly.
// Probed and rejected: 4-wave blocks w/ LDS x-stage (R12, +3.4µs), 2-j ILP
// (R7, neutral), recompute-v (R10, spill), tighter launch bounds (R4, spill).
// LESSON (R4, R10): live set ~84 VGPR. Never bound/structure below it.
// Budget: dur = ~48µs harness d_ws-poison fill (81% HBM peak, untouchable)
//             + ~4µs staging + ~34µs main (latency plateau).

#define OH 15
#define OW 15
#define EPS_ 1e-8f

#define XT_ELEMS (2 * 32 * 32 * 512)        // 2,097,152 bf16 (4 MB)
#define WT_ELEMS (32 * 5 * 64 * 16)         // 163,840 bf16 (320 KB)

typedef float v2f __attribute__((ext_vector_type(2)));

__device__ __forceinline__ v2f pfma(float a, v2f b, v2f c) {
    return __builtin_elementwise_fma((v2f){a, a}, b, c);
}
__device__ __forceinline__ float b_lo(unsigned int u) {
    union { unsigned int i; float f; } c; c.i = u << 16; return c.f;
}
__device__ __forceinline__ float b_hi(unsigned int u) {
    union { unsigned int i; float f; } c; c.i = u & 0xFFFF0000u; return c.f;
}
__device__ __forceinline__ unsigned short f2bf(float f) {
    union { float f; unsigned int i; } c; c.f = f;
    return (unsigned short)((c.i + 0x7FFFu + ((c.i >> 16) & 1u)) >> 16); // RNE
}

// merged staging: [0, XT_ELEMS) casts x; [XT_ELEMS, +WT_ELEMS) permutes w
__global__ __launch_bounds__(256) void stage_kernel(
    const float* __restrict__ x, const float* __restrict__ w,
    unsigned short* __restrict__ xt, unsigned short* __restrict__ wt)
{
    const int tid = blockIdx.x * 256 + threadIdx.x;
    if (tid < XT_ELEMS) {
        xt[tid] = f2bf(x[tid]);
    } else {
        const int t2 = tid - XT_ELEMS;      // over WT_ELEMS
        const int j  = t2 / 5120;
        const int r  = t2 - j * 5120;
        const int k  = r >> 10;
        const int L  = (r >> 4) & 63;
        const int e  = r & 15;
        const int i  = L + 64 * k;
        wt[t2] = (i < 288) ? f2bf(w[(size_t)i * 512 + j * 16 + e])
                           : (unsigned short)0;
    }
}

template <bool PERM>
__global__ __launch_bounds__(64, 3) void convcaps_kernel(
    const void* __restrict__ xp,   // PERM ? bf16 xt : f32 x
    const void* __restrict__ wp_,  // PERM ? bf16 wt : f32 w
    float* __restrict__ out)       // (450,512)
{
    const int blk  = blockIdx.x;      // 0..14399
    const int n    = blk >> 5;        // patch 0..449
    const int j    = blk & 31;        // out capsule
    const int lane = threadIdx.x;     // 0..63

    const int batch = n / (OH * OW);
    const int rem   = n - batch * OH * OW;
    const int oy    = rem / OW;
    const int ox    = rem - oy * OW;

    const bool has5 = (lane < 32);

    v2f v[5][8];                      // v[k][p*2+qq]
    // inactive 5th slot: logit = -inf so exp -> 0 (drops has5 selects later)
    float logit[5] = {0.f, 0.f, 0.f, 0.f, has5 ? 0.f : -1e30f};

    // ---- v[k] = X_i(4x4) * W_ij(4x4), i = lane + 64k ----
#pragma unroll
    for (int k = 0; k < 5; ++k) {
        if (k == 4 && !has5) {
#pragma unroll
            for (int m = 0; m < 8; ++m) v[4][m] = (v2f){0.f, 0.f};
        } else {
            const int i  = lane + 64 * k;
            const int a  = i & 31;
            const int kw = (i >> 5) % 3;
            const int kh = i / 96;
            const int h  = oy * 2 + kh;
            const int wc = ox * 2 + kw;
            const int pixel = (batch * 32 + h) * 32 + wc;

            float xr[16];
            v2f wr2[4][2];
            if (PERM) {
                // xt[pixel][a][16] bf16: 32B contiguous per lane
                const uint4* xb = reinterpret_cast<const uint4*>(
                    (const unsigned short*)xp + ((size_t)pixel * 512 + a * 16));
                uint4 u0 = xb[0], u1 = xb[1];
                xr[0]=b_lo(u0.x); xr[1]=b_hi(u0.x); xr[2]=b_lo(u0.y); xr[3]=b_hi(u0.y);
                xr[4]=b_lo(u0.z); xr[5]=b_hi(u0.z); xr[6]=b_lo(u0.w); xr[7]=b_hi(u0.w);
                xr[8]=b_lo(u1.x); xr[9]=b_hi(u1.x); xr[10]=b_lo(u1.y); xr[11]=b_hi(u1.y);
                xr[12]=b_lo(u1.z); xr[13]=b_hi(u1.z); xr[14]=b_lo(u1.w); xr[15]=b_hi(u1.w);
                // wt[j][k][lane][16] bf16: 32B contiguous per lane
                const uint4* wb = reinterpret_cast<const uint4*>(
                    (const unsigned short*)wp_ + (((size_t)j * 5 + k) * 64 + lane) * 16);
                uint4 q0 = wb[0], q1 = wb[1];
                wr2[0][0] = (v2f){b_lo(q0.x), b_hi(q0.x)};
                wr2[0][1] = (v2f){b_lo(q0.y), b_hi(q0.y)};
                wr2[1][0] = (v2f){b_lo(q0.z), b_hi(q0.z)};
                wr2[1][1] = (v2f){b_lo(q0.w), b_hi(q0.w)};
                wr2[2][0] = (v2f){b_lo(q1.x), b_hi(q1.x)};
                wr2[2][1] = (v2f){b_lo(q1.y), b_hi(q1.y)};
                wr2[3][0] = (v2f){b_lo(q1.z), b_hi(q1.z)};
                wr2[3][1] = (v2f){b_lo(q1.w), b_hi(q1.w)};
            } else {
                const float4* xv = reinterpret_cast<const float4*>(
                    (const float*)xp + ((size_t)pixel * 512 + a * 16));
                float4 x0 = xv[0], x1 = xv[1], x2 = xv[2], x3 = xv[3];
                float t_[16] = { x0.x,x0.y,x0.z,x0.w, x1.x,x1.y,x1.z,x1.w,
                                 x2.x,x2.y,x2.z,x2.w, x3.x,x3.y,x3.z,x3.w };
#pragma unroll
                for (int e = 0; e < 16; ++e) xr[e] = t_[e];
                const float4* wq = reinterpret_cast<const float4*>(
                    (const float*)wp_ + ((size_t)i * 32 + j) * 16);
                float4 w0 = wq[0], w1 = wq[1], w2 = wq[2], w3 = wq[3];
                wr2[0][0]=(v2f){w0.x,w0.y}; wr2[0][1]=(v2f){w0.z,w0.w};
                wr2[1][0]=(v2f){w1.x,w1.y}; wr2[1][1]=(v2f){w1.z,w1.w};
                wr2[2][0]=(v2f){w2.x,w2.y}; wr2[2][1]=(v2f){w2.z,w2.w};
                wr2[3][0]=(v2f){w3.x,w3.y}; wr2[3][1]=(v2f){w3.z,w3.w};
            }

#pragma unroll
            for (int p = 0; p < 4; ++p) {
#pragma unroll
                for (int qq = 0; qq < 2; ++qq) {
                    v2f acc = (v2f){0.f, 0.f};
                    acc = pfma(xr[p*4+0], wr2[0][qq], acc);
                    acc = pfma(xr[p*4+1], wr2[1][qq], acc);
                    acc = pfma(xr[p*4+2], wr2[2][qq], acc);
                    acc = pfma(xr[p*4+3], wr2[3][qq], acc);
                    v[k][p*2+qq] = acc;
                }
            }
        }
    }

#pragma unroll
    for (int it = 0; it < 3; ++it) {
        v2f c2[8];
        float se_loc;
        if (it == 0) {
#pragma unroll
            for (int m = 0; m < 8; ++m)
                c2[m] = v[0][m] + v[1][m] + v[2][m] + v[3][m] + v[4][m];
            se_loc = 0.f;  // normalizer is 288 (softmax of zeros)
        } else {
            const float e0 = __expf(logit[0]), e1 = __expf(logit[1]);
            const float e2 = __expf(logit[2]), e3 = __expf(logit[3]);
            const float e4 = __expf(logit[4]);   // 0 for lanes >= 32
#pragma unroll
            for (int m = 0; m < 8; ++m)
                c2[m] = pfma(e0, v[0][m],
                        pfma(e1, v[1][m],
                        pfma(e2, v[2][m],
                        pfma(e3, v[3][m],
                        pfma(e4, v[4][m], (v2f){0.f, 0.f})))));
            se_loc = e0 + e1 + e2 + e3 + e4;
        }

        float c[16];
#pragma unroll
        for (int m = 0; m < 8; ++m) { c[2*m] = c2[m].x; c[2*m+1] = c2[m].y; }

        // ---- split-first butterfly: comp bit b -> lane bit b ----
        float seR = se_loc;
        float s8[8];
        {
            const bool b = lane & 1;
#pragma unroll
            for (int m = 0; m < 8; ++m) {
                float send = b ? c[2*m]   : c[2*m+1];
                float keep = b ? c[2*m+1] : c[2*m];
                s8[m] = keep + __shfl_xor(send, 1);
            }
            if (it > 0) seR += __shfl_xor(seR, 1);
        }
        float s4[4];
        {
            const bool b = (lane >> 1) & 1;
#pragma unroll
            for (int m = 0; m < 4; ++m) {
                float send = b ? s8[2*m]   : s8[2*m+1];
                float keep = b ? s8[2*m+1] : s8[2*m];
                s4[m] = keep + __shfl_xor(send, 2);
            }
            if (it > 0) seR += __shfl_xor(seR, 2);
        }
        float s2v[2];
        {
            const bool b = (lane >> 2) & 1;
#pragma unroll
            for (int m = 0; m < 2; ++m) {
                float send = b ? s4[2*m]   : s4[2*m+1];
                float keep = b ? s4[2*m+1] : s4[2*m];
                s2v[m] = keep + __shfl_xor(send, 4);
            }
            if (it > 0) seR += __shfl_xor(seR, 4);
        }
        float s1;
        {
            const bool b = (lane >> 3) & 1;
            float send = b ? s2v[0] : s2v[1];
            float keep = b ? s2v[1] : s2v[0];
            s1 = keep + __shfl_xor(send, 8);
            if (it > 0) seR += __shfl_xor(seR, 8);
        }
        s1 += __shfl_xor(s1, 16);  if (it > 0) seR += __shfl_xor(seR, 16);
        s1 += __shfl_xor(s1, 32);  if (it > 0) seR += __shfl_xor(seR, 32);
        // s1 = sum_i (e_i or 1) * v_i[comp], comp = lane&15 ; seR = SE

        const float s = (it == 0) ? s1 * (1.0f / 288.0f) : s1 / seR;

        // ---- squash ----
        float t2 = s * s;
        t2 += __shfl_xor(t2, 1);
        t2 += __shfl_xor(t2, 2);
        t2 += __shfl_xor(t2, 4);
        t2 += __shfl_xor(t2, 8);
        const float n2 = t2;
        const float scale = n2 / ((1.0f + n2) * sqrtf(n2 + EPS_));
        const float pval = s * scale;   // comp (lane&15) of p

        if (it < 2) {
            float p[16];
#pragma unroll
            for (int q = 0; q < 16; ++q) p[q] = __shfl(pval, q);
            v2f p2[8];
#pragma unroll
            for (int m = 0; m < 8; ++m) p2[m] = (v2f){p[2*m], p[2*m+1]};
#pragma unroll
            for (int k = 0; k < 5; ++k) {
                v2f acc = (v2f){0.f, 0.f};
#pragma unroll
                for (int m = 0; m < 8; ++m)
                    acc = __builtin_elementwise_fma(v[k][m], p2[m], acc);
                logit[k] += acc.x + acc.y;
            }
        } else {
            if (lane < 16)
                out[(size_t)n * 512 + j * 16 + lane] = pval;
        }
    }
}

extern "C" void kernel_launch(void* const* d_in, const int* in_sizes, int n_in,
                              void* d_out, int out_size, void* d_ws, size_t ws_size,
                              hipStream_t stream) {
    const float* x = (const float*)d_in[0];
    const float* w = (const float*)d_in[1];
    float* out = (float*)d_out;
    const int nblocks = 450 * 32;   // one wave per (n, j)

    const size_t need = (size_t)(XT_ELEMS + WT_ELEMS) * sizeof(unsigned short);
    if (d_ws != nullptr && ws_size >= need) {
        unsigned short* xt = (unsigned short*)d_ws;
        unsigned short* wt = xt + XT_ELEMS;
        stage_kernel<<<(XT_ELEMS + WT_ELEMS) / 256, 256, 0, stream>>>(x, w, xt, wt);
        convcaps_kernel<true><<<nblocks, 64, 0, stream>>>(xt, wt, out);
    } else {
        convcaps_kernel<false><<<nblocks, 64, 0, stream>>>(x, w, out);
    }
}